// Round 3
// baseline (191.064 us; speedup 1.0000x reference)
//
#include <hip/hip_runtime.h>

// LSTM: T=512, B=4096, IN=1, H=12.
// R13: 2 cells/wave + gate-pair split -> 2048 waves = 2 waves/SIMD.
// Rationale (R12 counters: dur 122.5us = 574 cyc/step, VALUBusy 51%,
// Occ 10.7% = 1 wave/SIMD): per-step VALU exec is only ~250 cyc; ~55% of
// the step is dependency bubble (LDS h round trip + 2 serial exp2->rcp
// pairs) and with ONE wave per SIMD there is no second stream to fill it.
// Cells (4096) cap wave count, so halve cells/wave to double waves:
//  - lane>>5 = cell (2/wave), (lane>>4)&1 = gate-half, lane&15 = j slot.
//  - half0 computes the (i,f) pk-pair for j, half1 the (g,o) pk-pair,
//    packed along the GATE axis: K is the fma chain -> matvec is
//    12 pkfma + 1 init (vs 24+4 in R12), trans 6 (vs 10).
//  - activation marriage via 2x ds_swizzle_b32 xor16 (offset 0x401F):
//    half0 receives (tgS, so) from half1. No cndmask: half1's mirror
//    c/h state is garbage-but-finite (r's in (0,1), fma/exp2/rcp chain
//    can reach inf but never NaN; rcp(inf)=0 absorbs it; nothing from
//    half1 is ever read).
//  - h publish: half0 j-lanes ds_write_b32 (cell rows on disjoint banks
//    -> conflict-free, fixes R12's 3-way write alias), broadcast back as
//    3x ds_read_b128 per lane (2 addrs/instr, disjoint banks).
//  - fc in-lane over broadcast h, DELAYED one step (R11 trick: fills the
//    exp2->rcp windows; fake t=0 store aliases out[0], overwritten next
//    step; epilogue flushes t=511).
// Per-wave exec ~154 cyc, chain ~280-300; 2 resident waves -> wall/step
// ~ max(2*154, chain) ~ 310-360 cyc vs 574. X staged per chunk as float2
// (2 cells) -> more line overfetch but HBM is at 5% of peak (non-issue).
//
// Retained: pre-scaled gates (sigmoid -log2e, tanh +2log2e) so acts are
// rcp(1+exp2(g)); pre-scaled cell c2 = 2log2e*c; X chunk staging with
// one-chunk global prefetch + one-group xq prefetch; XPAD=68.

#define TT    512
#define NB    4096
#define HH    12
#define RPW   2      // cells per wave
#define CHUNK 64     // X staging chunk; TT % CHUNK == 0
#define XPAD  68     // padded x row stride (floats)
#define HSTR  20     // h row stride (floats): rows land on disjoint banks

typedef float v2f __attribute__((ext_vector_type(2)));
typedef float v4f __attribute__((ext_vector_type(4)));

static __device__ __forceinline__ v2f pkfma(v2f a, v2f b, v2f c) {
#if __has_builtin(__builtin_elementwise_fma)
    return __builtin_elementwise_fma(a, b, c);
#else
    v2f r; r.x = fmaf(a.x, b.x, c.x); r.y = fmaf(a.y, b.y, c.y); return r;
#endif
}
static __device__ __forceinline__ v2f splat2(float s) { v2f r; r.x = s; r.y = s; return r; }

#define SNEG   (-1.44269504088896340736f)   // sigmoid pre-scale: -log2(e)
#define SPOS   ( 2.88539008177792681472f)   // tanh pre-scale: +2*log2(e)
#define M2SPOS (-5.77078016355585362944f)   // -2*SPOS

#define SWZ_XOR16 0x401F                    // BitMode: and=0x1F, xor=16

__global__ __launch_bounds__(64, 2)
void lstm_fused(const float* __restrict__ X,
                const float* __restrict__ W_ih,
                const float* __restrict__ W_hh,
                const float* __restrict__ b_ih,
                const float* __restrict__ b_hh,
                const float* __restrict__ fc_w,
                const float* __restrict__ fc_b,
                float* __restrict__ out)
{
    __shared__ __align__(16) float xchunk[RPW][XPAD]; // [cell][time]
    __shared__ __align__(16) float hsh[RPW][HSTR];    // [cell][h-slot]

    const int lane = threadIdx.x;          // 0..63
    const int cell = lane >> 5;            // 0..1 : cell within wave
    const int half = (lane >> 4) & 1;      // 0: (i,f)  1: (g,o)
    const int j    = lane & 15;            // 0..11 real, 12..15 clones
    const int cellbase = blockIdx.x * RPW;
    const int gcell = cellbase + cell;     // global cell id

    const int jr = (j < HH) ? j : (HH - 1);   // clamp clones (finite)

    // ---- gate-pair weights, K-scalar packed: wK[k] = (wA[k], wB[k])
    // half0: A=i (SNEG), B=f (SNEG);  half1: A=g (SPOS), B=o (SNEG)
    const int   gA = (half ? 2 : 0) * HH + jr;
    const int   gB = (half ? 3 : 1) * HH + jr;
    const float sA = half ? SPOS : SNEG;
    const float* WA = W_hh + gA * HH;
    const float* WB = W_hh + gB * HH;
    v2f wK[12];
    #pragma unroll
    for (int k = 0; k < 12; ++k) {
        wK[k].x = sA   * WA[k];
        wK[k].y = SNEG * WB[k];
    }
    v2f wxv, bv;
    wxv.x = sA   * W_ih[gA];               // IN == 1, W_ih flat [48]
    wxv.y = SNEG * W_ih[gB];
    bv.x  = sA   * (b_ih[gA] + b_hh[gA]);
    bv.y  = SNEG * (b_ih[gB] + b_hh[gB]);

    // fc weights, K-pair packed (consumes broadcast h pairs)
    v2f fcv[6], bFCv;
    #pragma unroll
    for (int k = 0; k < 6; ++k) { fcv[k].x = fc_w[2 * k]; fcv[k].y = fc_w[2 * k + 1]; }
    bFCv.x = fc_b[0];  bFCv.y = 0.0f;

    float c2 = 0.0f;     // pre-scaled cell state (valid in half0 lanes)
    float hn = 0.0f;

    float* const hrow = &hsh[cell][0];

    // delayed-output state (R11 trick)
    unsigned offPrev = 0;
    float* const outp = out + gcell;

    // h0 = 0
    if (!half) hrow[j] = 0.0f;
    __builtin_amdgcn_wave_barrier();

    // prefetch chunk 0 of X: X[t=lane][cellbase + 0..1]
    float2 gq = *(const float2*)(X + (size_t)lane * NB + cellbase);

    for (int tc = 0; tc < TT; tc += CHUNK) {
        xchunk[0][lane] = gq.x;            // cell0 row, time slot = lane
        xchunk[1][lane] = gq.y;            // cell1 row
        if (tc + CHUNK < TT)
            gq = *(const float2*)(X + (size_t)(tc + CHUNK + lane) * NB + cellbase);
        __builtin_amdgcn_wave_barrier();   // order staging vs xq reads

        float4 xq_next = *(const float4*)&xchunk[cell][0];

        for (int t4 = 0; t4 < CHUNK; t4 += 4) {
            const float4 xq = xq_next;                       // group t4
            const int nx = (t4 + 4 < CHUNK) ? (t4 + 4) : t4; // clamp tail
            xq_next = *(const float4*)&xchunk[cell][nx];
            const float xs[4] = {xq.x, xq.y, xq.z, xq.w};

            #pragma unroll
            for (int u = 0; u < 4; ++u) {
                // broadcast-read my cell's h_{t-1} (3x ds_read_b128,
                // 2 addresses per instr on disjoint banks)
                const v4f ha = *(const v4f*)&hrow[0];
                const v4f hb = *(const v4f*)&hrow[4];
                const v4f hc = *(const v4f*)&hrow[8];

                // gate pair: init (x-proj + bias), then K-chain of 12,
                // split into two 6-deep accumulators
                v2f aA = pkfma(splat2(xs[u]), wxv, bv);
                v2f aB; aB.x = 0.0f; aB.y = 0.0f;
                aA = pkfma(wK[0],  splat2(ha.x), aA);
                aB = pkfma(wK[1],  splat2(ha.y), aB);
                aA = pkfma(wK[2],  splat2(ha.z), aA);
                aB = pkfma(wK[3],  splat2(ha.w), aB);
                aA = pkfma(wK[4],  splat2(hb.x), aA);
                aB = pkfma(wK[5],  splat2(hb.y), aB);
                aA = pkfma(wK[6],  splat2(hb.z), aA);
                aB = pkfma(wK[7],  splat2(hb.w), aB);
                aA = pkfma(wK[8],  splat2(hc.x), aA);
                aB = pkfma(wK[9],  splat2(hc.y), aB);
                aA = pkfma(wK[10], splat2(hc.z), aA);
                aB = pkfma(wK[11], splat2(hc.w), aB);
                const v2f a = aA + aB;

                const float E0 = __builtin_amdgcn_exp2f(a.x);
                const float E1 = __builtin_amdgcn_exp2f(a.y);

                // fc of h_{t-1} (delayed output): filler for trans/swz
                v2f hp0; hp0.x = ha.x; hp0.y = ha.y;
                v2f hp1; hp1.x = ha.z; hp1.y = ha.w;
                v2f hp2; hp2.x = hb.x; hp2.y = hb.y;
                v2f hp3; hp3.x = hb.z; hp3.y = hb.w;
                v2f hp4; hp4.x = hc.x; hp4.y = hc.y;
                v2f hp5; hp5.x = hc.z; hp5.y = hc.w;
                v2f pf = pkfma(fcv[0], hp0, bFCv);
                pf = pkfma(fcv[1], hp1, pf);
                pf = pkfma(fcv[2], hp2, pf);
                pf = pkfma(fcv[3], hp3, pf);
                pf = pkfma(fcv[4], hp4, pf);
                pf = pkfma(fcv[5], hp5, pf);

                const float r0 = __builtin_amdgcn_rcpf(1.0f + E0); // si | rg
                const float r1 = __builtin_amdgcn_rcpf(1.0f + E1); // sf | so
                const float t0 = fmaf(M2SPOS, r0, SPOS);           // -- | tgS

                // marry the halves: half0 receives half1's (tgS, so).
                // half1 receives half0's values -> garbage-but-finite.
                const float x0 = __int_as_float(
                    __builtin_amdgcn_ds_swizzle(__float_as_int(t0), SWZ_XOR16));
                const float x1 = __int_as_float(
                    __builtin_amdgcn_ds_swizzle(__float_as_int(r1), SWZ_XOR16));

                // delayed output store (fills the swz/trans window)
                const float p = pf.x + pf.y;
                if ((lane & 31) == 0) *(float*)((char*)outp + offPrev) = p;

                // c/h update (meaningful in half0; half1 garbage-finite:
                // r's in (0,1) so inf possible but never NaN; rcp absorbs)
                c2 = fmaf(r1, c2, r0 * x0);
                const float Ec = __builtin_amdgcn_exp2f(c2);
                const float rc = __builtin_amdgcn_rcpf(1.0f + Ec);
                hn = fmaf(-2.0f * x1, rc, x1);

                if (!half) hrow[j] = hn;     // publish h_t (slots 0..15)
                __builtin_amdgcn_wave_barrier();

                offPrev = (unsigned)(tc + t4 + u) << 14;   // t * NB * 4B
            }
        }
    }

    // epilogue: fc(h_511) -> out[511]
    {
        const v4f ha = *(const v4f*)&hrow[0];
        const v4f hb = *(const v4f*)&hrow[4];
        const v4f hc = *(const v4f*)&hrow[8];
        v2f hp0; hp0.x = ha.x; hp0.y = ha.y;
        v2f hp1; hp1.x = ha.z; hp1.y = ha.w;
        v2f hp2; hp2.x = hb.x; hp2.y = hb.y;
        v2f hp3; hp3.x = hb.z; hp3.y = hb.w;
        v2f hp4; hp4.x = hc.x; hp4.y = hc.y;
        v2f hp5; hp5.x = hc.z; hp5.y = hc.w;
        v2f pf = pkfma(fcv[0], hp0, bFCv);
        pf = pkfma(fcv[1], hp1, pf);
        pf = pkfma(fcv[2], hp2, pf);
        pf = pkfma(fcv[3], hp3, pf);
        pf = pkfma(fcv[4], hp4, pf);
        pf = pkfma(fcv[5], hp5, pf);
        const float p = pf.x + pf.y;
        if ((lane & 31) == 0) *(float*)((char*)outp + offPrev) = p;
    }
}

extern "C" void kernel_launch(void* const* d_in, const int* in_sizes, int n_in,
                              void* d_out, int out_size, void* d_ws, size_t ws_size,
                              hipStream_t stream) {
    const float* X    = (const float*)d_in[0];
    const float* W_ih = (const float*)d_in[1];
    const float* W_hh = (const float*)d_in[2];
    const float* b_ih = (const float*)d_in[3];
    const float* b_hh = (const float*)d_in[4];
    const float* fc_w = (const float*)d_in[5];
    const float* fc_b = (const float*)d_in[6];
    float* out = (float*)d_out;

    const int grid = NB / RPW;   // 2048 single-wave blocks: 2 waves/SIMD
    lstm_fused<<<grid, 64, 0, stream>>>(X, W_ih, W_hh, b_ih, b_hh, fc_w, fc_b, out);
}